// Round 12
// baseline (114.980 us; speedup 1.0000x reference)
//
#include <hip/hip_runtime.h>

#define BATCH 16
#define SEQ   2048
#define DIM   64
#define QT    32
#define KC    128
#define NCH   (SEQ / KC)   // 16
#define NTHREADS 256

typedef __bf16 bf16x8 __attribute__((ext_vector_type(8)));
typedef float  f32x4  __attribute__((ext_vector_type(4)));
typedef unsigned short u16;

__device__ __forceinline__ f32x4 ldf32x4(const unsigned char* sm, int row, int off) {
    return *reinterpret_cast<const f32x4*>(sm + row * 512 + (off ^ ((row & 7) << 4)));
}

__device__ __forceinline__ bf16x8 cvt8(f32x4 a, f32x4 b) {
    bf16x8 r;
    r[0] = (__bf16)a[0]; r[1] = (__bf16)a[1]; r[2] = (__bf16)a[2]; r[3] = (__bf16)a[3];
    r[4] = (__bf16)b[0]; r[5] = (__bf16)b[1]; r[6] = (__bf16)b[2]; r[7] = (__bf16)b[3];
    return r;
}

// ---------------- merged prepass ----------------
// blocks [0,2048): Q (scaled, fragment-major) + K (row-major swizzled)  [verified r6/r7]
// blocks [2048,2304): V -> V^T (fragment-major)                          [verified r5/r8]
__global__ __launch_bounds__(256)
void prep_all(const float* __restrict__ qg, const float* __restrict__ kg,
              const float* __restrict__ vg,
              u16* __restrict__ qpk, u16* __restrict__ kpk, u16* __restrict__ vtpk)
{
    __shared__ float t[128][65];
    const int tid = threadIdx.x;
    const int bx  = blockIdx.x;

    if (bx < 2048) {
        int gid = bx * 256 + tid;
        const int HALF = BATCH * SEQ * 8;      // 262144 threads per tensor
        bool isq = gid < HALF;
        int u = isq ? gid : gid - HALF;
        int row = u >> 3, blk = u & 7;
        const float* src = (isq ? qg : kg) + (size_t)row * DIM + blk * 8;
        f32x4 v0 = __builtin_nontemporal_load(reinterpret_cast<const f32x4*>(src));
        f32x4 v1 = __builtin_nontemporal_load(reinterpret_cast<const f32x4*>(src + 4));
        float sc = isq ? 0.125f : 1.0f;
        bf16x8 o;
        o[0]=(__bf16)(v0[0]*sc); o[1]=(__bf16)(v0[1]*sc); o[2]=(__bf16)(v0[2]*sc); o[3]=(__bf16)(v0[3]*sc);
        o[4]=(__bf16)(v1[0]*sc); o[5]=(__bf16)(v1[1]*sc); o[6]=(__bf16)(v1[2]*sc); o[7]=(__bf16)(v1[3]*sc);
        int b = row >> 11, s = row & 2047;
        char* dst;
        if (isq) {
            int qt = s >> 5, rr = s & 31;
            int rt = rr >> 4, l = rr & 15;
            int ks = blk >> 2, g = blk & 3;
            dst = (char*)qpk + ((size_t)(b * 64 + qt)) * 4096 + (rt * 2 + ks) * 1024 + (g * 16 + l) * 16;
        } else {
            int c = s >> 7, r = s & 127;
            dst = (char*)kpk + ((size_t)(b * 16 + c)) * 16384 + r * 128 + ((blk * 16) ^ ((r & 7) << 4));
        }
        *reinterpret_cast<bf16x8*>(dst) = o;
    } else {
        int vb = bx - 2048;
        int b = vb >> 4, c = vb & 15;
        const float* src = vg + ((size_t)b * SEQ + c * KC) * DIM;
        #pragma unroll
        for (int i = 0; i < 8; ++i) {
            int idx = tid + i * 256;               // 0..2047
            int k = idx >> 4, dblk = idx & 15;
            f32x4 v = __builtin_nontemporal_load(
                reinterpret_cast<const f32x4*>(src + k * 64 + dblk * 4));
            t[k][dblk * 4 + 0] = v[0]; t[k][dblk * 4 + 1] = v[1];
            t[k][dblk * 4 + 2] = v[2]; t[k][dblk * 4 + 3] = v[3];
        }
        __syncthreads();
        #pragma unroll
        for (int i = 0; i < 4; ++i) {
            int u = tid + i * 256;                 // 0..1023
            int d = u >> 4, kblk = u & 15;
            bf16x8 o;
            #pragma unroll
            for (int j = 0; j < 8; ++j) o[j] = (__bf16)t[kblk * 8 + j][d];
            int w = d >> 4, l = d & 15, ks4 = kblk >> 2, g = kblk & 3;
            char* dst = (char*)vtpk + ((size_t)(b * 16 + c)) * 16384 + (w * 4 + ks4) * 1024 + (g * 16 + l) * 16;
            *reinterpret_cast<bf16x8*>(dst) = o;
        }
    }
}

// ---------------- main attention ----------------
__global__ __launch_bounds__(NTHREADS, 2)
void attn_main(const u16* __restrict__ qpk, const u16* __restrict__ kpk,
               const u16* __restrict__ vtpk, float* __restrict__ out)
{
    // Only P transposes through LDS. Pad pins LDS > 53.3 KB -> exactly 2 blocks/CU
    // (the proven regime; >=3 blocks/CU caused FETCH explosions in r4/r5/r6).
    __shared__ unsigned char p32_sm[2][16384];// [32 q][128 k] fp32, swizzled, double-buffered
    __shared__ unsigned char lds_pad[22528];  // occupancy governor (stats live here)
    float* sm_l    = (float*)lds_pad;         // [4][32]
    float* fin_inv = (float*)(lds_pad + 512); // [32]

    const int tid  = threadIdx.x;
    const int wave = tid >> 6;
    const int lane = tid & 63;
    const int l15  = lane & 15;
    const int grp  = lane >> 4;

    int raw = blockIdx.x;
    int bid = (raw & 7) * 128 + (raw >> 3);  // XCD-chunked swizzle, 1024 % 8 == 0
    const int b  = bid >> 6;
    const int qt = bid & 63;
    const int q0 = qt * QT;

    const char* qsrc  = (const char*)qpk + (size_t)bid * 4096;
    const char* kbase = (const char*)kpk + (size_t)b * NCH * 16384;
    const char* vbase = (const char*)vtpk + (size_t)b * NCH * 16384 + wave * 4096 + lane * 16;
    float* outO = out + ((size_t)b * SEQ + q0) * DIM;
    float* outP = out + (size_t)BATCH * SEQ * DIM + ((size_t)b * SEQ + q0) * SEQ;

    // Q fragments: direct global->reg (fragment-major, wave-invariant)
    bf16x8 qa[2][2];
    #pragma unroll
    for (int rt = 0; rt < 2; ++rt)
        #pragma unroll
        for (int ks = 0; ks < 2; ++ks)
            qa[rt][ks] = *reinterpret_cast<const bf16x8*>(qsrc + (rt * 2 + ks) * 1024 + lane * 16);

    // per-wave K fragment read off the packed swizzled image (rows wave*32..+31 only)
    auto loadK = [&](bf16x8 kf[4], int c) {
        const char* p = kbase + (size_t)c * 16384;
        const int row0 = wave * 32 + l15;
        const int swz  = (l15 & 7) << 4;
        #pragma unroll
        for (int ks = 0; ks < 2; ++ks)
            #pragma unroll
            for (int h = 0; h < 2; ++h) {
                int off = ks * 64 + grp * 16;
                kf[ks * 2 + h] = *reinterpret_cast<const bf16x8*>(
                    p + (row0 + h * 16) * 128 + (off ^ swz));
            }
    };
    auto loadV = [&](bf16x8 vf[4], int c) {
        const char* p = vbase + (size_t)c * 16384;
        #pragma unroll
        for (int i = 0; i < 4; ++i)
            vf[i] = *reinterpret_cast<const bf16x8*>(p + i * 1024);
    };
    auto qk_mfma = [&](const bf16x8 kf[4], f32x4 acc[2][2]) {
        #pragma unroll
        for (int rt = 0; rt < 2; ++rt)
            #pragma unroll
            for (int h = 0; h < 2; ++h)
                acc[rt][h] = f32x4{0.f, 0.f, 0.f, 0.f};
        #pragma unroll
        for (int ks = 0; ks < 2; ++ks) {
            acc[0][0] = __builtin_amdgcn_mfma_f32_16x16x32_bf16(qa[0][ks], kf[ks * 2 + 0], acc[0][0], 0, 0, 0);
            acc[0][1] = __builtin_amdgcn_mfma_f32_16x16x32_bf16(qa[0][ks], kf[ks * 2 + 1], acc[0][1], 0, 0, 0);
            acc[1][0] = __builtin_amdgcn_mfma_f32_16x16x32_bf16(qa[1][ks], kf[ks * 2 + 0], acc[1][0], 0, 0, 0);
            acc[1][1] = __builtin_amdgcn_mfma_f32_16x16x32_bf16(qa[1][ks], kf[ks * 2 + 1], acc[1][1], 0, 0, 0);
        }
    };

    // ===== pass 1: barrier-free register streaming (r11, verified) =====
    float lsum[2][4];
    #pragma unroll
    for (int rt = 0; rt < 2; ++rt)
        #pragma unroll
        for (int r = 0; r < 4; ++r) lsum[rt][r] = 0.f;

    {
        bf16x8 kf[4], kn[4];
        loadK(kf, 0);
        for (int c = 0; c < NCH; ++c) {
            if (c + 1 < NCH) loadK(kn, c + 1);   // 1-deep prefetch
            f32x4 acc[2][2];
            qk_mfma(kf, acc);
            #pragma unroll
            for (int rt = 0; rt < 2; ++rt)
                #pragma unroll
                for (int r = 0; r < 4; ++r)
                    lsum[rt][r] += __expf(acc[rt][0][r]) + __expf(acc[rt][1][r]);
            #pragma unroll
            for (int i = 0; i < 4; ++i) kf[i] = kn[i];
        }
    }

    // row-sum reduction: 16 lanes (cols) then 4 waves (col tiles)
    #pragma unroll
    for (int rt = 0; rt < 2; ++rt)
        #pragma unroll
        for (int r = 0; r < 4; ++r) {
            float s = lsum[rt][r];
            s += __shfl_xor(s, 1); s += __shfl_xor(s, 2);
            s += __shfl_xor(s, 4); s += __shfl_xor(s, 8);
            if (l15 == 0) sm_l[wave * 32 + rt * 16 + grp * 4 + r] = s;
        }
    __syncthreads();
    if (tid < QT) {
        float L = sm_l[tid] + sm_l[32 + tid] + sm_l[64 + tid] + sm_l[96 + tid];
        fin_inv[tid] = 1.0f / L;
    }
    __syncthreads();
    float pinv[2][4];
    #pragma unroll
    for (int rt = 0; rt < 2; ++rt)
        #pragma unroll
        for (int r = 0; r < 4; ++r)
            pinv[rt][r] = fin_inv[rt * 16 + grp * 4 + r];

    // ===== pass 2: K,V in registers (1-chunk-ahead prefetch); ONE barrier/chunk;
    //       only P goes through LDS (r10/r11 cadence, k_sm eliminated) =====
    f32x4 oacc0 = f32x4{0.f, 0.f, 0.f, 0.f};
    f32x4 oacc1 = f32x4{0.f, 0.f, 0.f, 0.f};

    bf16x8 kc_[4], kn_[4], vc_[4], vn_[4];
    loadK(kc_, 0);
    loadV(vc_, 0);

    for (int c = 0; c < NCH; ++c) {
        // prefetch next chunk's K,V: in flight across QK+exp+P-write, drained at the barrier
        if (c + 1 < NCH) { loadK(kn_, c + 1); loadV(vn_, c + 1); }

        f32x4 acc[2][2];
        qk_mfma(kc_, acc);

        unsigned char* pb = p32_sm[c & 1];
        #pragma unroll
        for (int rt = 0; rt < 2; ++rt)
            #pragma unroll
            for (int ct = 0; ct < 2; ++ct)
                #pragma unroll
                for (int r = 0; r < 4; ++r) {
                    int qrow = rt * 16 + grp * 4 + r;
                    int kcol = wave * 32 + ct * 16 + l15;
                    float p = __expf(acc[rt][ct][r]) * pinv[rt][r];
                    *reinterpret_cast<float*>(&pb[qrow * 512 + ((kcol * 4) ^ ((qrow & 7) << 4))]) = p;
                }
        __syncthreads();   // P visible; kn_/vn_ landed; prev chunk's NT stores drained

        // PV: A = P rows (fp32->bf16 in-register), B = V^T fragments from regs
        #pragma unroll
        for (int ks4 = 0; ks4 < 4; ++ks4) {
            int off = ks4 * 128 + grp * 32;
            f32x4 a00 = ldf32x4(pb, l15, off);
            f32x4 a01 = ldf32x4(pb, l15, off + 16);
            f32x4 a10 = ldf32x4(pb, 16 + l15, off);
            f32x4 a11 = ldf32x4(pb, 16 + l15, off + 16);
            bf16x8 pa0 = cvt8(a00, a01);
            bf16x8 pa1 = cvt8(a10, a11);
            oacc0 = __builtin_amdgcn_mfma_f32_16x16x32_bf16(pa0, vc_[ks4], oacc0, 0, 0, 0);
            oacc1 = __builtin_amdgcn_mfma_f32_16x16x32_bf16(pa1, vc_[ks4], oacc1, 0, 0, 0);
        }

        // coalesced attn write: 512B contiguous per 32-lane group, NON-TEMPORAL
        // drains at NEXT chunk's barrier (covered by its QK+exp)
        #pragma unroll
        for (int i = 0; i < 4; ++i) {
            int idx = tid + i * 256;
            int row = idx >> 5, colb = (idx & 31) * 16;
            f32x4 val = *reinterpret_cast<const f32x4*>(
                &pb[row * 512 + (colb ^ ((row & 7) << 4))]);
            __builtin_nontemporal_store(val,
                reinterpret_cast<f32x4*>(outP + (size_t)row * SEQ + c * KC + (idx & 31) * 4));
        }

        #pragma unroll
        for (int i = 0; i < 4; ++i) { kc_[i] = kn_[i]; vc_[i] = vn_[i]; }
    }

    // O write (non-temporal)
    #pragma unroll
    for (int r = 0; r < 4; ++r) {
        int qrow = grp * 4 + r;
        __builtin_nontemporal_store(oacc0[r],
            outO + (size_t)qrow * DIM + wave * 16 + l15);
        __builtin_nontemporal_store(oacc1[r],
            outO + (size_t)(16 + qrow) * DIM + wave * 16 + l15);
    }
}

extern "C" void kernel_launch(void* const* d_in, const int* in_sizes, int n_in,
                              void* d_out, int out_size, void* d_ws, size_t ws_size,
                              hipStream_t stream) {
    (void)in_sizes; (void)n_in; (void)out_size; (void)ws_size;
    const float* q = (const float*)d_in[0];
    const float* k = (const float*)d_in[1];
    const float* v = (const float*)d_in[2];
    float* out = (float*)d_out;

    char* ws = (char*)d_ws;
    u16* qpk  = (u16*)ws;                     // 4 MB
    u16* kpk  = (u16*)(ws + (4 << 20));       // 4 MB
    u16* vtpk = (u16*)(ws + (8 << 20));       // 4 MB

    prep_all<<<dim3(2048 + BATCH * NCH), dim3(256), 0, stream>>>(q, k, v, qpk, kpk, vtpk);
    attn_main<<<dim3(BATCH * (SEQ / QT)), dim3(256), 0, stream>>>(qpk, kpk, vtpk, out);
}

// Round 13
// 91.443 us; speedup vs baseline: 1.2574x; 1.2574x over previous
//
#include <hip/hip_runtime.h>

#define BATCH 16
#define SEQ   2048
#define DIM   64
#define QT    32
#define KC    128
#define NCH   (SEQ / KC)   // 16
#define NTHREADS 256

typedef __bf16 bf16x8 __attribute__((ext_vector_type(8)));
typedef float  f32x4  __attribute__((ext_vector_type(4)));
typedef unsigned short u16;

// async global->LDS, 16B per lane. LDS dest must be wave-uniform; global src per-lane.
__device__ __forceinline__ void gl_lds16(const void* g, void* l) {
    __builtin_amdgcn_global_load_lds(
        (const __attribute__((address_space(1))) unsigned int*)g,
        (__attribute__((address_space(3))) unsigned int*)l, 16, 0, 0);
}

// swizzled 16B LDS fragment load
__device__ __forceinline__ bf16x8 ldfrag(const unsigned char* sm, int row, int stride, int off) {
    return *reinterpret_cast<const bf16x8*>(sm + row * stride + (off ^ ((row & 7) << 4)));
}
__device__ __forceinline__ f32x4 ldf32x4(const unsigned char* sm, int row, int off) {
    return *reinterpret_cast<const f32x4*>(sm + row * 512 + (off ^ ((row & 7) << 4)));
}

__device__ __forceinline__ bf16x8 cvt8(f32x4 a, f32x4 b) {
    bf16x8 r;
    r[0] = (__bf16)a[0]; r[1] = (__bf16)a[1]; r[2] = (__bf16)a[2]; r[3] = (__bf16)a[3];
    r[4] = (__bf16)b[0]; r[5] = (__bf16)b[1]; r[6] = (__bf16)b[2]; r[7] = (__bf16)b[3];
    return r;
}

// ---------------- prepass: Q (scaled, fragment-major) + K (row-major swizzled) ----------------
__global__ __launch_bounds__(256)
void prep_qk(const float* __restrict__ qg, const float* __restrict__ kg,
             u16* __restrict__ qpk, u16* __restrict__ kpk)
{
    int gid = blockIdx.x * 256 + threadIdx.x;
    const int HALF = BATCH * SEQ * 8;      // 262144 threads per tensor
    bool isq = gid < HALF;
    int u = isq ? gid : gid - HALF;
    int row = u >> 3, blk = u & 7;
    const float* src = (isq ? qg : kg) + (size_t)row * DIM + blk * 8;
    f32x4 v0 = __builtin_nontemporal_load(reinterpret_cast<const f32x4*>(src));
    f32x4 v1 = __builtin_nontemporal_load(reinterpret_cast<const f32x4*>(src + 4));
    float sc = isq ? 0.125f : 1.0f;
    bf16x8 o;
    o[0]=(__bf16)(v0[0]*sc); o[1]=(__bf16)(v0[1]*sc); o[2]=(__bf16)(v0[2]*sc); o[3]=(__bf16)(v0[3]*sc);
    o[4]=(__bf16)(v1[0]*sc); o[5]=(__bf16)(v1[1]*sc); o[6]=(__bf16)(v1[2]*sc); o[7]=(__bf16)(v1[3]*sc);
    int b = row >> 11, s = row & 2047;
    char* dst;
    if (isq) {
        // fragment-major: block (rt*2+ks) x 1KB, byte (g*16+l)*16  [verified r6/r7]
        int qt = s >> 5, rr = s & 31;
        int rt = rr >> 4, l = rr & 15;
        int ks = blk >> 2, g = blk & 3;
        dst = (char*)qpk + ((size_t)(b * 64 + qt)) * 4096 + (rt * 2 + ks) * 1024 + (g * 16 + l) * 16;
    } else {
        // row-major 128B rows, XOR-swizzled (gl_lds image)
        int c = s >> 7, r = s & 127;
        dst = (char*)kpk + ((size_t)(b * 16 + c)) * 16384 + r * 128 + ((blk * 16) ^ ((r & 7) << 4));
    }
    *reinterpret_cast<bf16x8*>(dst) = o;
}

// ---------------- prepass: V -> V^T bf16, fragment-major packed [verified r5/r8] ----------------
// V^T chunk (b,c): 16KB = blocks (w*4+ks4) x 1KB; byte (g*16+l)*16 = V^T[w*16+l][k bytes ks4*64+g*16]
__global__ __launch_bounds__(256)
void prep_vt(const float* __restrict__ vg, u16* __restrict__ vtpk)
{
    __shared__ float t[128][65];
    int b = blockIdx.x >> 4, c = blockIdx.x & 15;
    const float* src = vg + ((size_t)b * SEQ + c * KC) * DIM;
    int tid = threadIdx.x;
    #pragma unroll
    for (int i = 0; i < 8; ++i) {
        int idx = tid + i * 256;               // 0..2047
        int k = idx >> 4, dblk = idx & 15;
        f32x4 v = __builtin_nontemporal_load(
            reinterpret_cast<const f32x4*>(src + k * 64 + dblk * 4));
        t[k][dblk * 4 + 0] = v[0]; t[k][dblk * 4 + 1] = v[1];
        t[k][dblk * 4 + 2] = v[2]; t[k][dblk * 4 + 3] = v[3];
    }
    __syncthreads();
    #pragma unroll
    for (int i = 0; i < 4; ++i) {
        int u = tid + i * 256;                 // 0..1023
        int d = u >> 4, kblk = u & 15;
        bf16x8 o;
        #pragma unroll
        for (int j = 0; j < 8; ++j) o[j] = (__bf16)t[kblk * 8 + j][d];
        int w = d >> 4, l = d & 15, ks4 = kblk >> 2, g = kblk & 3;
        char* dst = (char*)vtpk + ((size_t)(b * 16 + c)) * 16384 + (w * 4 + ks4) * 1024 + (g * 16 + l) * 16;
        *reinterpret_cast<bf16x8*>(dst) = o;
    }
}

// ---------------- main attention ----------------
__global__ __launch_bounds__(NTHREADS, 2)
void attn_main(const u16* __restrict__ qpk, const u16* __restrict__ kpk,
               const u16* __restrict__ vtpk, float* __restrict__ out)
{
    // 64.6 KB -> 2 blocks/CU (the proven regime)
    __shared__ unsigned char k_sm[2][16384];  // [128 k][64 d] bf16 swizzled, double-buffered
    __shared__ unsigned char p32_sm[2][16384];// [32 q][128 k] fp32, swizzled, double-buffered
    __shared__ float sm_l[4][QT];
    __shared__ float fin_inv[QT];

    const int tid  = threadIdx.x;
    const int wave = tid >> 6;
    const int lane = tid & 63;
    const int l15  = lane & 15;
    const int grp  = lane >> 4;

    int raw = blockIdx.x;
    int bid = (raw & 7) * 128 + (raw >> 3);  // XCD-chunked swizzle, 1024 % 8 == 0
    const int b  = bid >> 6;
    const int qt = bid & 63;
    const int q0 = qt * QT;

    const char* qsrc  = (const char*)qpk + (size_t)bid * 4096;
    const char* kbase = (const char*)kpk + (size_t)b * NCH * 16384;
    const char* vbase = (const char*)vtpk + (size_t)b * NCH * 16384 + wave * 4096 + lane * 16;
    float* outO = out + ((size_t)b * SEQ + q0) * DIM;
    float* outP = out + (size_t)BATCH * SEQ * DIM + ((size_t)b * SEQ + q0) * SEQ;

    auto stage_tile = [&](const char* src, unsigned char* dst) {
        #pragma unroll
        for (int i = 0; i < 4; ++i)
            gl_lds16(src + i * 4096 + wave * 1024 + lane * 16, dst + i * 4096 + wave * 1024);
    };

    // prologue: K(0) for PASS 2 staged now (has all of pass 1 to land);
    // Q direct global->reg (fragment-major, wave-invariant)
    stage_tile(kbase, k_sm[0]);
    bf16x8 qa[2][2];
    #pragma unroll
    for (int rt = 0; rt < 2; ++rt)
        #pragma unroll
        for (int ks = 0; ks < 2; ++ks)
            qa[rt][ks] = *reinterpret_cast<const bf16x8*>(qsrc + (rt * 2 + ks) * 1024 + lane * 16);

    // ===== pass 1: barrier-free. Wave w reads ONLY K rows w*32..+31 (no cross-wave
    // sharing) -> direct global->reg fragment reads off the packed swizzled image =====
    auto loadK1 = [&](bf16x8 kf[4], int c) {
        const char* p = kbase + (size_t)c * 16384;
        const int row0 = wave * 32 + l15;
        const int swz  = (l15 & 7) << 4;
        #pragma unroll
        for (int ks = 0; ks < 2; ++ks)
            #pragma unroll
            for (int h = 0; h < 2; ++h) {
                int off = ks * 64 + grp * 16;
                kf[ks * 2 + h] = *reinterpret_cast<const bf16x8*>(
                    p + (row0 + h * 16) * 128 + (off ^ swz));
            }
    };

    float lsum[2][4];
    #pragma unroll
    for (int rt = 0; rt < 2; ++rt)
        #pragma unroll
        for (int r = 0; r < 4; ++r) lsum[rt][r] = 0.f;

    {
        bf16x8 kf[4], kn[4];
        loadK1(kf, 0);
        for (int c = 0; c < NCH; ++c) {
            if (c + 1 < NCH) loadK1(kn, c + 1);   // 1-deep prefetch, compiler-pipelined
            f32x4 acc[2][2];
            #pragma unroll
            for (int rt = 0; rt < 2; ++rt)
                #pragma unroll
                for (int h = 0; h < 2; ++h)
                    acc[rt][h] = f32x4{0.f, 0.f, 0.f, 0.f};
            #pragma unroll
            for (int ks = 0; ks < 2; ++ks) {
                acc[0][0] = __builtin_amdgcn_mfma_f32_16x16x32_bf16(qa[0][ks], kf[ks * 2 + 0], acc[0][0], 0, 0, 0);
                acc[0][1] = __builtin_amdgcn_mfma_f32_16x16x32_bf16(qa[0][ks], kf[ks * 2 + 1], acc[0][1], 0, 0, 0);
                acc[1][0] = __builtin_amdgcn_mfma_f32_16x16x32_bf16(qa[1][ks], kf[ks * 2 + 0], acc[1][0], 0, 0, 0);
                acc[1][1] = __builtin_amdgcn_mfma_f32_16x16x32_bf16(qa[1][ks], kf[ks * 2 + 1], acc[1][1], 0, 0, 0);
            }
            #pragma unroll
            for (int rt = 0; rt < 2; ++rt)
                #pragma unroll
                for (int r = 0; r < 4; ++r)
                    lsum[rt][r] += __expf(acc[rt][0][r]) + __expf(acc[rt][1][r]);
            #pragma unroll
            for (int i = 0; i < 4; ++i) kf[i] = kn[i];
        }
    }

    // row-sum reduction: 16 lanes (cols) then 4 waves (col tiles)
    #pragma unroll
    for (int rt = 0; rt < 2; ++rt)
        #pragma unroll
        for (int r = 0; r < 4; ++r) {
            float s = lsum[rt][r];
            s += __shfl_xor(s, 1); s += __shfl_xor(s, 2);
            s += __shfl_xor(s, 4); s += __shfl_xor(s, 8);
            if (l15 == 0) sm_l[wave][rt * 16 + grp * 4 + r] = s;
        }
    __syncthreads();   // also drains prologue K(0) gl_lds
    if (tid < QT) {
        float L = sm_l[0][tid] + sm_l[1][tid] + sm_l[2][tid] + sm_l[3][tid];
        fin_inv[tid] = 1.0f / L;
    }
    __syncthreads();
    float pinv[2][4];
    #pragma unroll
    for (int rt = 0; rt < 2; ++rt)
        #pragma unroll
        for (int r = 0; r < 4; ++r)
            pinv[rt][r] = fin_inv[rt * 16 + grp * 4 + r];

    auto compute_qk = [&](const unsigned char* kbuf, f32x4 acc[2][2]) {
        #pragma unroll
        for (int rt = 0; rt < 2; ++rt)
            #pragma unroll
            for (int ct = 0; ct < 2; ++ct)
                acc[rt][ct] = f32x4{0.f, 0.f, 0.f, 0.f};
        const int cb = wave * 32;
        #pragma unroll
        for (int ks = 0; ks < 2; ++ks) {
            int off = ks * 64 + grp * 16;
            bf16x8 b0 = ldfrag(kbuf, cb + l15,      128, off);
            bf16x8 b1 = ldfrag(kbuf, cb + 16 + l15, 128, off);
            acc[0][0] = __builtin_amdgcn_mfma_f32_16x16x32_bf16(qa[0][ks], b0, acc[0][0], 0, 0, 0);
            acc[0][1] = __builtin_amdgcn_mfma_f32_16x16x32_bf16(qa[0][ks], b1, acc[0][1], 0, 0, 0);
            acc[1][0] = __builtin_amdgcn_mfma_f32_16x16x32_bf16(qa[1][ks], b0, acc[1][0], 0, 0, 0);
            acc[1][1] = __builtin_amdgcn_mfma_f32_16x16x32_bf16(qa[1][ks], b1, acc[1][1], 0, 0, 0);
        }
    };

    // ===== pass 2: ONE barrier per chunk (round-10 structure, unchanged) =====
    f32x4 oacc0 = f32x4{0.f, 0.f, 0.f, 0.f};
    f32x4 oacc1 = f32x4{0.f, 0.f, 0.f, 0.f};

    for (int c = 0; c < NCH; ++c) {
        const int cur = c & 1;

        // V(c): fragment-major global->reg; consumed after the barrier
        bf16x8 vf[4];
        {
            const char* p = vbase + (size_t)c * 16384;
            #pragma unroll
            for (int i = 0; i < 4; ++i)
                vf[i] = *reinterpret_cast<const bf16x8*>(p + i * 1024);
        }

        // K(c+1): staged now, drained by this chunk's barrier, read next chunk
        if (c + 1 < NCH)
            stage_tile(kbase + (size_t)(c + 1) * 16384, k_sm[cur ^ 1]);

        f32x4 acc[2][2];
        compute_qk(k_sm[cur], acc);

        unsigned char* pb = p32_sm[cur];
        #pragma unroll
        for (int rt = 0; rt < 2; ++rt)
            #pragma unroll
            for (int ct = 0; ct < 2; ++ct)
                #pragma unroll
                for (int r = 0; r < 4; ++r) {
                    int qrow = rt * 16 + grp * 4 + r;
                    int kcol = wave * 32 + ct * 16 + l15;
                    float p = __expf(acc[rt][ct][r]) * pinv[rt][r];
                    *reinterpret_cast<float*>(&pb[qrow * 512 + ((kcol * 4) ^ ((qrow & 7) << 4))]) = p;
                }
        __syncthreads();   // drains K(c+1)+V(c) vmem, P visible; prev P-stores drained too

        // PV: A = P rows (fp32->bf16 in-register), B = V^T fragments from regs
        #pragma unroll
        for (int ks4 = 0; ks4 < 4; ++ks4) {
            int off = ks4 * 128 + grp * 32;
            f32x4 a00 = ldf32x4(pb, l15, off);
            f32x4 a01 = ldf32x4(pb, l15, off + 16);
            f32x4 a10 = ldf32x4(pb, 16 + l15, off);
            f32x4 a11 = ldf32x4(pb, 16 + l15, off + 16);
            bf16x8 pa0 = cvt8(a00, a01);
            bf16x8 pa1 = cvt8(a10, a11);
            oacc0 = __builtin_amdgcn_mfma_f32_16x16x32_bf16(pa0, vf[ks4], oacc0, 0, 0, 0);
            oacc1 = __builtin_amdgcn_mfma_f32_16x16x32_bf16(pa1, vf[ks4], oacc1, 0, 0, 0);
        }

        // coalesced attn write: 512B contiguous per 32-lane group, NON-TEMPORAL
        // drains at NEXT chunk's barrier (covered by its QK+exp)
        #pragma unroll
        for (int i = 0; i < 4; ++i) {
            int idx = tid + i * 256;
            int row = idx >> 5, colb = (idx & 31) * 16;
            f32x4 val = *reinterpret_cast<const f32x4*>(
                &pb[row * 512 + (colb ^ ((row & 7) << 4))]);
            __builtin_nontemporal_store(val,
                reinterpret_cast<f32x4*>(outP + (size_t)row * SEQ + c * KC + (idx & 31) * 4));
        }
    }

    // O write (non-temporal)
    #pragma unroll
    for (int r = 0; r < 4; ++r) {
        int qrow = grp * 4 + r;
        __builtin_nontemporal_store(oacc0[r],
            outO + (size_t)qrow * DIM + wave * 16 + l15);
        __builtin_nontemporal_store(oacc1[r],
            outO + (size_t)(16 + qrow) * DIM + wave * 16 + l15);
    }
}

extern "C" void kernel_launch(void* const* d_in, const int* in_sizes, int n_in,
                              void* d_out, int out_size, void* d_ws, size_t ws_size,
                              hipStream_t stream) {
    (void)in_sizes; (void)n_in; (void)out_size; (void)ws_size;
    const float* q = (const float*)d_in[0];
    const float* k = (const float*)d_in[1];
    const float* v = (const float*)d_in[2];
    float* out = (float*)d_out;

    char* ws = (char*)d_ws;
    u16* qpk  = (u16*)ws;                     // 4 MB
    u16* kpk  = (u16*)(ws + (4 << 20));       // 4 MB
    u16* vtpk = (u16*)(ws + (8 << 20));       // 4 MB

    prep_qk<<<dim3(2048), dim3(256), 0, stream>>>(q, k, qpk, kpk);
    prep_vt<<<dim3(BATCH * NCH), dim3(256), 0, stream>>>(v, vtpk);
    attn_main<<<dim3(BATCH * (SEQ / QT)), dim3(256), 0, stream>>>(qpk, kpk, vtpk, out);
}

// Round 14
// 89.265 us; speedup vs baseline: 1.2881x; 1.0244x over previous
//
#include <hip/hip_runtime.h>

#define BATCH 16
#define SEQ   2048
#define DIM   64
#define QT    32
#define KC    128
#define NCH   (SEQ / KC)   // 16
#define NTHREADS 256

typedef __bf16 bf16x8 __attribute__((ext_vector_type(8)));
typedef float  f32x4  __attribute__((ext_vector_type(4)));
typedef unsigned short u16;

// async global->LDS, 16B per lane. LDS dest must be wave-uniform; global src per-lane.
__device__ __forceinline__ void gl_lds16(const void* g, void* l) {
    __builtin_amdgcn_global_load_lds(
        (const __attribute__((address_space(1))) unsigned int*)g,
        (__attribute__((address_space(3))) unsigned int*)l, 16, 0, 0);
}

// swizzled 16B LDS fragment load
__device__ __forceinline__ bf16x8 ldfrag(const unsigned char* sm, int row, int stride, int off) {
    return *reinterpret_cast<const bf16x8*>(sm + row * stride + (off ^ ((row & 7) << 4)));
}
__device__ __forceinline__ f32x4 ldf32x4(const unsigned char* sm, int row, int off) {
    return *reinterpret_cast<const f32x4*>(sm + row * 512 + (off ^ ((row & 7) << 4)));
}

__device__ __forceinline__ bf16x8 cvt8(f32x4 a, f32x4 b) {
    bf16x8 r;
    r[0] = (__bf16)a[0]; r[1] = (__bf16)a[1]; r[2] = (__bf16)a[2]; r[3] = (__bf16)a[3];
    r[4] = (__bf16)b[0]; r[5] = (__bf16)b[1]; r[6] = (__bf16)b[2]; r[7] = (__bf16)b[3];
    return r;
}

// ---------------- prepass: Q (scaled, fragment-major) + K (row-major swizzled) ----------------
__global__ __launch_bounds__(256)
void prep_qk(const float* __restrict__ qg, const float* __restrict__ kg,
             u16* __restrict__ qpk, u16* __restrict__ kpk)
{
    int gid = blockIdx.x * 256 + threadIdx.x;
    const int HALF = BATCH * SEQ * 8;      // 262144 threads per tensor
    bool isq = gid < HALF;
    int u = isq ? gid : gid - HALF;
    int row = u >> 3, blk = u & 7;
    const float* src = (isq ? qg : kg) + (size_t)row * DIM + blk * 8;
    f32x4 v0 = __builtin_nontemporal_load(reinterpret_cast<const f32x4*>(src));
    f32x4 v1 = __builtin_nontemporal_load(reinterpret_cast<const f32x4*>(src + 4));
    float sc = isq ? 0.125f : 1.0f;
    bf16x8 o;
    o[0]=(__bf16)(v0[0]*sc); o[1]=(__bf16)(v0[1]*sc); o[2]=(__bf16)(v0[2]*sc); o[3]=(__bf16)(v0[3]*sc);
    o[4]=(__bf16)(v1[0]*sc); o[5]=(__bf16)(v1[1]*sc); o[6]=(__bf16)(v1[2]*sc); o[7]=(__bf16)(v1[3]*sc);
    int b = row >> 11, s = row & 2047;
    char* dst;
    if (isq) {
        // fragment-major: block (rt*2+ks) x 1KB, byte (g*16+l)*16  [verified r6/r7]
        int qt = s >> 5, rr = s & 31;
        int rt = rr >> 4, l = rr & 15;
        int ks = blk >> 2, g = blk & 3;
        dst = (char*)qpk + ((size_t)(b * 64 + qt)) * 4096 + (rt * 2 + ks) * 1024 + (g * 16 + l) * 16;
    } else {
        // row-major 128B rows, XOR-swizzled (gl_lds image)
        int c = s >> 7, r = s & 127;
        dst = (char*)kpk + ((size_t)(b * 16 + c)) * 16384 + r * 128 + ((blk * 16) ^ ((r & 7) << 4));
    }
    *reinterpret_cast<bf16x8*>(dst) = o;
}

// ---------------- prepass: V -> V^T bf16, fragment-major packed [verified r5/r8] ----------------
// V^T chunk (b,c): 16KB = blocks (w*4+ks4) x 1KB; byte (g*16+l)*16 = V^T[w*16+l][k bytes ks4*64+g*16]
__global__ __launch_bounds__(256)
void prep_vt(const float* __restrict__ vg, u16* __restrict__ vtpk)
{
    __shared__ float t[128][65];
    int b = blockIdx.x >> 4, c = blockIdx.x & 15;
    const float* src = vg + ((size_t)b * SEQ + c * KC) * DIM;
    int tid = threadIdx.x;
    #pragma unroll
    for (int i = 0; i < 8; ++i) {
        int idx = tid + i * 256;               // 0..2047
        int k = idx >> 4, dblk = idx & 15;
        f32x4 v = __builtin_nontemporal_load(
            reinterpret_cast<const f32x4*>(src + k * 64 + dblk * 4));
        t[k][dblk * 4 + 0] = v[0]; t[k][dblk * 4 + 1] = v[1];
        t[k][dblk * 4 + 2] = v[2]; t[k][dblk * 4 + 3] = v[3];
    }
    __syncthreads();
    #pragma unroll
    for (int i = 0; i < 4; ++i) {
        int u = tid + i * 256;                 // 0..1023
        int d = u >> 4, kblk = u & 15;
        bf16x8 o;
        #pragma unroll
        for (int j = 0; j < 8; ++j) o[j] = (__bf16)t[kblk * 8 + j][d];
        int w = d >> 4, l = d & 15, ks4 = kblk >> 2, g = kblk & 3;
        char* dst = (char*)vtpk + ((size_t)(b * 16 + c)) * 16384 + (w * 4 + ks4) * 1024 + (g * 16 + l) * 16;
        *reinterpret_cast<bf16x8*>(dst) = o;
    }
}

// ---------------- main attention ----------------
__global__ __launch_bounds__(NTHREADS, 2)
void attn_main(const u16* __restrict__ qpk, const u16* __restrict__ kpk,
               const u16* __restrict__ vtpk, float* __restrict__ out)
{
    // 64.6 KB -> 2 blocks/CU (the proven regime)
    __shared__ unsigned char k_sm[2][16384];  // [128 k][64 d] bf16 swizzled, double-buffered
    __shared__ unsigned char p32_sm[2][16384];// [32 q][128 k] fp32, swizzled, double-buffered
    __shared__ float sm_l[4][QT];
    __shared__ float fin_inv[QT];

    const int tid  = threadIdx.x;
    const int wave = tid >> 6;
    const int lane = tid & 63;
    const int l15  = lane & 15;
    const int grp  = lane >> 4;

    int raw = blockIdx.x;
    int bid = (raw & 7) * 128 + (raw >> 3);  // XCD-chunked swizzle, 1024 % 8 == 0
    const int b  = bid >> 6;
    const int qt = bid & 63;
    const int q0 = qt * QT;

    const char* qsrc  = (const char*)qpk + (size_t)bid * 4096;
    const char* kbase = (const char*)kpk + (size_t)b * NCH * 16384;
    const char* vbase = (const char*)vtpk + (size_t)b * NCH * 16384 + wave * 4096 + lane * 16;
    float* outO = out + ((size_t)b * SEQ + q0) * DIM;
    float* outP = out + (size_t)BATCH * SEQ * DIM + ((size_t)b * SEQ + q0) * SEQ;

    auto stage_tile = [&](const char* src, unsigned char* dst) {
        #pragma unroll
        for (int i = 0; i < 4; ++i)
            gl_lds16(src + i * 4096 + wave * 1024 + lane * 16, dst + i * 4096 + wave * 1024);
    };

    // prologue: K(0) for PASS 2 staged now (has all of pass 1 to land);
    // Q direct global->reg (fragment-major, wave-invariant)
    stage_tile(kbase, k_sm[0]);
    bf16x8 qa[2][2];
    #pragma unroll
    for (int rt = 0; rt < 2; ++rt)
        #pragma unroll
        for (int ks = 0; ks < 2; ++ks)
            qa[rt][ks] = *reinterpret_cast<const bf16x8*>(qsrc + (rt * 2 + ks) * 1024 + lane * 16);

    // ===== pass 1: barrier-free. Wave w reads ONLY K rows w*32..+31 (no cross-wave
    // sharing) -> direct global->reg fragment reads off the packed swizzled image =====
    auto loadK1 = [&](bf16x8 kf[4], int c) {
        const char* p = kbase + (size_t)c * 16384;
        const int row0 = wave * 32 + l15;
        const int swz  = (l15 & 7) << 4;
        #pragma unroll
        for (int ks = 0; ks < 2; ++ks)
            #pragma unroll
            for (int h = 0; h < 2; ++h) {
                int off = ks * 64 + grp * 16;
                kf[ks * 2 + h] = *reinterpret_cast<const bf16x8*>(
                    p + (row0 + h * 16) * 128 + (off ^ swz));
            }
    };

    float lsum[2][4];
    #pragma unroll
    for (int rt = 0; rt < 2; ++rt)
        #pragma unroll
        for (int r = 0; r < 4; ++r) lsum[rt][r] = 0.f;

    {
        bf16x8 kf[4], kn[4];
        loadK1(kf, 0);
        for (int c = 0; c < NCH; ++c) {
            if (c + 1 < NCH) loadK1(kn, c + 1);   // 1-deep prefetch, compiler-pipelined
            f32x4 acc[2][2];
            #pragma unroll
            for (int rt = 0; rt < 2; ++rt)
                #pragma unroll
                for (int h = 0; h < 2; ++h)
                    acc[rt][h] = f32x4{0.f, 0.f, 0.f, 0.f};
            __builtin_amdgcn_s_setprio(1);   // T5: favor MFMA cluster vs other block's VALU
            #pragma unroll
            for (int ks = 0; ks < 2; ++ks) {
                acc[0][0] = __builtin_amdgcn_mfma_f32_16x16x32_bf16(qa[0][ks], kf[ks * 2 + 0], acc[0][0], 0, 0, 0);
                acc[0][1] = __builtin_amdgcn_mfma_f32_16x16x32_bf16(qa[0][ks], kf[ks * 2 + 1], acc[0][1], 0, 0, 0);
                acc[1][0] = __builtin_amdgcn_mfma_f32_16x16x32_bf16(qa[1][ks], kf[ks * 2 + 0], acc[1][0], 0, 0, 0);
                acc[1][1] = __builtin_amdgcn_mfma_f32_16x16x32_bf16(qa[1][ks], kf[ks * 2 + 1], acc[1][1], 0, 0, 0);
            }
            __builtin_amdgcn_s_setprio(0);
            #pragma unroll
            for (int rt = 0; rt < 2; ++rt)
                #pragma unroll
                for (int r = 0; r < 4; ++r)
                    lsum[rt][r] += __expf(acc[rt][0][r]) + __expf(acc[rt][1][r]);
            #pragma unroll
            for (int i = 0; i < 4; ++i) kf[i] = kn[i];
        }
    }

    // row-sum reduction: 16 lanes (cols) then 4 waves (col tiles)
    #pragma unroll
    for (int rt = 0; rt < 2; ++rt)
        #pragma unroll
        for (int r = 0; r < 4; ++r) {
            float s = lsum[rt][r];
            s += __shfl_xor(s, 1); s += __shfl_xor(s, 2);
            s += __shfl_xor(s, 4); s += __shfl_xor(s, 8);
            if (l15 == 0) sm_l[wave][rt * 16 + grp * 4 + r] = s;
        }
    __syncthreads();   // also drains prologue K(0) gl_lds
    if (tid < QT) {
        float L = sm_l[0][tid] + sm_l[1][tid] + sm_l[2][tid] + sm_l[3][tid];
        fin_inv[tid] = 1.0f / L;
    }
    __syncthreads();
    float pinv[2][4];
    #pragma unroll
    for (int rt = 0; rt < 2; ++rt)
        #pragma unroll
        for (int r = 0; r < 4; ++r)
            pinv[rt][r] = fin_inv[rt * 16 + grp * 4 + r];

    auto compute_qk = [&](const unsigned char* kbuf, f32x4 acc[2][2]) {
        #pragma unroll
        for (int rt = 0; rt < 2; ++rt)
            #pragma unroll
            for (int ct = 0; ct < 2; ++ct)
                acc[rt][ct] = f32x4{0.f, 0.f, 0.f, 0.f};
        const int cb = wave * 32;
        __builtin_amdgcn_s_setprio(1);   // T5
        #pragma unroll
        for (int ks = 0; ks < 2; ++ks) {
            int off = ks * 64 + grp * 16;
            bf16x8 b0 = ldfrag(kbuf, cb + l15,      128, off);
            bf16x8 b1 = ldfrag(kbuf, cb + 16 + l15, 128, off);
            acc[0][0] = __builtin_amdgcn_mfma_f32_16x16x32_bf16(qa[0][ks], b0, acc[0][0], 0, 0, 0);
            acc[0][1] = __builtin_amdgcn_mfma_f32_16x16x32_bf16(qa[0][ks], b1, acc[0][1], 0, 0, 0);
            acc[1][0] = __builtin_amdgcn_mfma_f32_16x16x32_bf16(qa[1][ks], b0, acc[1][0], 0, 0, 0);
            acc[1][1] = __builtin_amdgcn_mfma_f32_16x16x32_bf16(qa[1][ks], b1, acc[1][1], 0, 0, 0);
        }
        __builtin_amdgcn_s_setprio(0);
    };

    // ===== pass 2: ONE barrier per chunk (round-10/11 structure, unchanged) =====
    f32x4 oacc0 = f32x4{0.f, 0.f, 0.f, 0.f};
    f32x4 oacc1 = f32x4{0.f, 0.f, 0.f, 0.f};

    for (int c = 0; c < NCH; ++c) {
        const int cur = c & 1;

        // V(c): fragment-major global->reg; consumed after the barrier
        bf16x8 vf[4];
        {
            const char* p = vbase + (size_t)c * 16384;
            #pragma unroll
            for (int i = 0; i < 4; ++i)
                vf[i] = *reinterpret_cast<const bf16x8*>(p + i * 1024);
        }

        // K(c+1): staged now, drained by this chunk's barrier, read next chunk
        if (c + 1 < NCH)
            stage_tile(kbase + (size_t)(c + 1) * 16384, k_sm[cur ^ 1]);

        f32x4 acc[2][2];
        compute_qk(k_sm[cur], acc);

        unsigned char* pb = p32_sm[cur];
        #pragma unroll
        for (int rt = 0; rt < 2; ++rt)
            #pragma unroll
            for (int ct = 0; ct < 2; ++ct)
                #pragma unroll
                for (int r = 0; r < 4; ++r) {
                    int qrow = rt * 16 + grp * 4 + r;
                    int kcol = wave * 32 + ct * 16 + l15;
                    float p = __expf(acc[rt][ct][r]) * pinv[rt][r];
                    *reinterpret_cast<float*>(&pb[qrow * 512 + ((kcol * 4) ^ ((qrow & 7) << 4))]) = p;
                }
        __syncthreads();   // drains K(c+1)+V(c) vmem, P visible; prev P-stores drained too

        // PV: A = P rows (fp32->bf16 in-register), B = V^T fragments from regs
        __builtin_amdgcn_s_setprio(1);   // T5
        #pragma unroll
        for (int ks4 = 0; ks4 < 4; ++ks4) {
            int off = ks4 * 128 + grp * 32;
            f32x4 a00 = ldf32x4(pb, l15, off);
            f32x4 a01 = ldf32x4(pb, l15, off + 16);
            f32x4 a10 = ldf32x4(pb, 16 + l15, off);
            f32x4 a11 = ldf32x4(pb, 16 + l15, off + 16);
            bf16x8 pa0 = cvt8(a00, a01);
            bf16x8 pa1 = cvt8(a10, a11);
            oacc0 = __builtin_amdgcn_mfma_f32_16x16x32_bf16(pa0, vf[ks4], oacc0, 0, 0, 0);
            oacc1 = __builtin_amdgcn_mfma_f32_16x16x32_bf16(pa1, vf[ks4], oacc1, 0, 0, 0);
        }
        __builtin_amdgcn_s_setprio(0);

        // coalesced attn write: 512B contiguous per 32-lane group, NON-TEMPORAL
        // drains at NEXT chunk's barrier (covered by its QK+exp)
        #pragma unroll
        for (int i = 0; i < 4; ++i) {
            int idx = tid + i * 256;
            int row = idx >> 5, colb = (idx & 31) * 16;
            f32x4 val = *reinterpret_cast<const f32x4*>(
                &pb[row * 512 + (colb ^ ((row & 7) << 4))]);
            __builtin_nontemporal_store(val,
                reinterpret_cast<f32x4*>(outP + (size_t)row * SEQ + c * KC + (idx & 31) * 4));
        }
    }

    // O write (non-temporal)
    #pragma unroll
    for (int r = 0; r < 4; ++r) {
        int qrow = grp * 4 + r;
        __builtin_nontemporal_store(oacc0[r],
            outO + (size_t)qrow * DIM + wave * 16 + l15);
        __builtin_nontemporal_store(oacc1[r],
            outO + (size_t)(16 + qrow) * DIM + wave * 16 + l15);
    }
}

extern "C" void kernel_launch(void* const* d_in, const int* in_sizes, int n_in,
                              void* d_out, int out_size, void* d_ws, size_t ws_size,
                              hipStream_t stream) {
    (void)in_sizes; (void)n_in; (void)out_size; (void)ws_size;
    const float* q = (const float*)d_in[0];
    const float* k = (const float*)d_in[1];
    const float* v = (const float*)d_in[2];
    float* out = (float*)d_out;

    char* ws = (char*)d_ws;
    u16* qpk  = (u16*)ws;                     // 4 MB
    u16* kpk  = (u16*)(ws + (4 << 20));       // 4 MB
    u16* vtpk = (u16*)(ws + (8 << 20));       // 4 MB

    prep_qk<<<dim3(2048), dim3(256), 0, stream>>>(q, k, qpk, kpk);
    prep_vt<<<dim3(BATCH * NCH), dim3(256), 0, stream>>>(v, vtpk);
    attn_main<<<dim3(BATCH * (SEQ / QT)), dim3(256), 0, stream>>>(qpk, kpk, vtpk, out);
}